// Round 8
// baseline (416.494 us; speedup 1.0000x reference)
//
#include <hip/hip_runtime.h>
#include <math.h>

// Problem constants
#define D_MODEL 2048
#define N_HEADS 16
#define N_KV    4
#define DH      128
#define QKV_DIM 3072   // 2048 + 2*4*128
#define TT      2048   // T
#define BB      2      // B
#define ROWS    (BB*TT)  // 4096

// LDS strides (u16 units)
#define VS_STRIDE 72    // 128 rows (d) x 64 kv (padded)
#define PS_STRIDE 72    // 16 rows (q) x 64 kv (padded)

typedef unsigned short u16;
typedef short short8 __attribute__((ext_vector_type(8)));
typedef short short4v __attribute__((ext_vector_type(4)));
typedef float float4v __attribute__((ext_vector_type(4)));

__device__ inline float b2f(u16 h) {
    union { unsigned u; float f; } v; v.u = ((unsigned)h) << 16; return v.f;
}
__device__ inline u16 f2b(float f) {
    union { float f; unsigned u; } v; v.f = f;
    unsigned r = v.u + 0x7FFF + ((v.u >> 16) & 1);
    return (u16)(r >> 16);
}

// async global->LDS DMA, 16 bytes/lane. LDS dest = wave-uniform base + lane*16.
__device__ inline void async16(const void* g, void* l) {
    __builtin_amdgcn_global_load_lds(
        (const __attribute__((address_space(1))) void*)g,
        (__attribute__((address_space(3))) void*)l, 16, 0, 0);
}

// ---------------------------------------------------------------------------
// fp32 -> bf16 bulk convert (vectorized)
__global__ void convert_f2b(const float* __restrict__ src, u16* __restrict__ dst) {
    int i = blockIdx.x * 256 + threadIdx.x;
    float4v a = *(const float4v*)(src + (size_t)i * 4);
    short4v p;
    p[0] = (short)f2b(a[0]); p[1] = (short)f2b(a[1]);
    p[2] = (short)f2b(a[2]); p[3] = (short)f2b(a[3]);
    *(short4v*)(dst + (size_t)i * 4) = p;
}

// ---------------------------------------------------------------------------
// 32x32 transpose + fp32->bf16: dst[c][r] = bf16(src[r][c + col0]). 256 thr.
__global__ void transpose_f2b(const float* __restrict__ src, u16* __restrict__ dst,
                              int R, int C, int col0) {
    __shared__ __align__(16) u16 tile[32][33];
    int bc = blockIdx.x * 32, br = blockIdx.y * 32;
    int tx = threadIdx.x & 31, ty = threadIdx.x >> 5;   // ty 0..7
    for (int i = ty; i < 32; i += 8)
        tile[i][tx] = f2b(src[(size_t)(br + i) * C + col0 + bc + tx]);
    __syncthreads();
    for (int i = ty; i < 32; i += 8)
        dst[(size_t)(bc + i) * R + br + tx] = tile[tx][i];
}

// ---------------------------------------------------------------------------
// m97-style async GEMM: C[M,N] = A[M,K] @ Bt[N,K]^T, bf16 in, fp32 accum.
// B^T split across two buffers at N-row `nsplit` (workspace tetris).
// ROPE: fused rotary on cols < 2560 (fast hw trig: __sinf/__cosf/__expf).
template<bool F32OUT, bool ROPE>
__global__ __launch_bounds__(256) void gemm_bt_async(
    const u16* __restrict__ A, const u16* __restrict__ Bt1, const u16* __restrict__ Bt2,
    int nsplit, void* __restrict__ Cv, int M, int N, int K, const int* __restrict__ sp) {
    __shared__ __align__(16) u16 As[128 * 32];
    __shared__ __align__(16) u16 Bs[128 * 32];
    const int tid = threadIdx.x;
    const int wave = tid >> 6, lane = tid & 63;
    const int quad = lane >> 4, l16 = lane & 15;
    const int bm = blockIdx.y * 128, bn = blockIdx.x * 128;
    const int wm = (wave >> 1) * 64, wn = (wave & 1) * 64;
    const int srow = wave * 32 + (lane >> 2);
    const int scol = (lane & 3) * 8;
    const u16* Bt = (bn < nsplit) ? (Bt1 + (size_t)bn * K)
                                  : (Bt2 + (size_t)(bn - nsplit) * K);

    float4v acc[4][4] = {};

    for (int k0 = 0; k0 < K; k0 += 32) {
        async16(A + (size_t)(bm + srow) * K + k0 + scol, (char*)As + wave * 2048);
        async16(A + (size_t)(bm + srow + 16) * K + k0 + scol, (char*)As + wave * 2048 + 1024);
        async16(Bt + (size_t)srow * K + k0 + scol, (char*)Bs + wave * 2048);
        async16(Bt + (size_t)(srow + 16) * K + k0 + scol, (char*)Bs + wave * 2048 + 1024);
        __syncthreads();
        short8 af[4], bf[4];
#pragma unroll
        for (int i = 0; i < 4; i++)
            af[i] = *(const short8*)(As + (wm + i * 16 + l16) * 32 + quad * 8);
#pragma unroll
        for (int j = 0; j < 4; j++)
            bf[j] = *(const short8*)(Bs + (wn + j * 16 + l16) * 32 + quad * 8);
#pragma unroll
        for (int i = 0; i < 4; i++)
#pragma unroll
            for (int j = 0; j < 4; j++)
                acc[i][j] = __builtin_amdgcn_mfma_f32_16x16x32_bf16(af[i], bf[j], acc[i][j], 0, 0, 0);
        __syncthreads();
    }
    const int sp0 = ROPE ? *sp : 0;
    // epilogue: C/D layout col=lane&15, row=quad*4+reg (m89/m91-verified).
    // j outer so the per-column inverse-frequency is computed once per j.
#pragma unroll
    for (int j = 0; j < 4; j++) {
        int col = bn + wn + j * 16 + l16;
        bool do_rope = ROPE && (col < 2560);
        float inv = 0.f;
        if (do_rope) inv = __expf(-0.14391156816f * (float)((col & 127) >> 1));
#pragma unroll
        for (int i = 0; i < 4; i++) {
            int row0 = bm + wm + i * 16 + quad * 4;
#pragma unroll
            for (int r = 0; r < 4; r++) {
                float v = acc[i][j][r];
                if (do_rope) {
                    float partner = __shfl_xor(v, 1, 64);
                    float ang = (float)(sp0 + ((row0 + r) & (TT - 1))) * inv;
                    float c = __cosf(ang), s = __sinf(ang);
                    v = (col & 1) ? (partner * s + v * c)
                                  : (v * c - partner * s);
                }
                if (F32OUT) ((float*)Cv)[(size_t)(row0 + r) * N + col] = v;
                else        ((u16*)Cv)[(size_t)(row0 + r) * N + col] = f2b(v);
            }
        }
    }
}

// ---------------------------------------------------------------------------
// Flash attention v5: 512 threads = 8 waves, q-tile 128 rows (16/wave).
// K staged via global_load_lds into an unpadded double buffer (prefetch for
// kt+1 issued during kt's compute; drained by next tile's first barrier).
// XCD swizzle: bx&7 -> (b,hk). Fixed-offset softmax; l via ones-column MFMA.
__global__ __launch_bounds__(512) void attn_kernel(
    const u16* __restrict__ qkv, u16* __restrict__ y) {
    __shared__ __align__(16) u16 Ks[2][64 * 128];          // 2 x 16384 B
    __shared__ __align__(16) u16 Vs[128 * VS_STRIDE];      // 18432 B
    __shared__ __align__(16) u16 Ps[8][16 * PS_STRIDE];    // 18432 B (total 69632)

    const int tid = threadIdx.x;
    const int wave = tid >> 6, lane = tid & 63;
    const int quad = lane >> 4, l16 = lane & 15;
    const int bx = blockIdx.x;
    const int xg = bx & 7;             // XCD group = (b, hk)
    const int b = xg >> 2, hk = xg & 3;
    const int jj = bx >> 3;            // 0..63 within group
    const int h = hk * 4 + (jj & 3);
    const int qq = jj >> 2;            // 0..15
    const int qt = (qq & 1) ? (15 - (qq >> 1)) : (qq >> 1);   // balance long/short
    const int qcol = h * 128;
    const int kcol = 2048 + hk * 128;
    const int vcol = 2560 + hk * 128;
    const float scale = 0.08838834764831845f;  // 1/sqrt(128)

    // Q fragments in registers (reused every kv-tile)
    const int wq0 = qt * 128 + wave * 16;
    const u16* qrow = qkv + (size_t)(b * TT + wq0 + l16) * QKV_DIM + qcol;
    short8 qf[4];
#pragma unroll
    for (int d = 0; d < 4; d++)
        qf[d] = *(const short8*)(qrow + d * 32 + quad * 8);

    // Oacc[0..7]: O tile (16 x 128). Oacc[8]: row-sum l via ones-column.
    float4v Oacc[9] = {};
    const short8 ONES = {(short)0x3F80, (short)0x3F80, (short)0x3F80, (short)0x3F80,
                         (short)0x3F80, (short)0x3F80, (short)0x3F80, (short)0x3F80};

    const int ktmax = 2 * qt + 1;

    // K async staging: wave w covers rows [w*8, w*8+8), 2 instructions of 1KB
    const size_t kgoff = (size_t)(wave * 8 + (lane >> 4)) * QKV_DIM + (lane & 15) * 8;
    // kt=0 prefetch: K via DMA, V via registers
    async16(qkv + (size_t)(b * TT) * QKV_DIM + kcol + kgoff, (char*)Ks[0] + wave * 2048);
    async16(qkv + (size_t)(b * TT + 4) * QKV_DIM + kcol + kgoff, (char*)Ks[0] + wave * 2048 + 1024);
    short8 vreg[2];
#pragma unroll
    for (int s = 0; s < 2; s++)
        vreg[s] = *(const short8*)(qkv + (size_t)(b * TT + lane) * QKV_DIM + vcol + (wave * 2 + s) * 8);

    for (int kt = 0; kt <= ktmax; kt++) {
        const u16* Kcur = Ks[kt & 1];
        __syncthreads();   // drains K-DMA + V prefetch; prev tile's readers done
        // commit V (transposed) to LDS: 2 lanes/bank pairs -> conflict-free
#pragma unroll
        for (int s = 0; s < 2; s++) {
            int dgi = wave * 2 + s;
#pragma unroll
            for (int j8 = 0; j8 < 8; j8++)
                Vs[(dgi * 8 + j8) * VS_STRIDE + lane] = (u16)vreg[s][j8];
        }
        __syncthreads();   // Vs visible
        if (kt < ktmax) {  // prefetch next tile (overlaps all compute below)
            const u16* kb = qkv + (size_t)(b * TT + (kt + 1) * 64) * QKV_DIM;
            async16(kb + kcol + kgoff, (char*)Ks[(kt + 1) & 1] + wave * 2048);
            async16(kb + (size_t)4 * QKV_DIM + kcol + kgoff,
                    (char*)Ks[(kt + 1) & 1] + wave * 2048 + 1024);
#pragma unroll
            for (int s = 0; s < 2; s++)
                vreg[s] = *(const short8*)(kb + (size_t)lane * QKV_DIM + vcol + (wave * 2 + s) * 8);
        }

        // S = Q*K^T
        float4v S[4] = {};
#pragma unroll
        for (int d = 0; d < 4; d++) {
#pragma unroll
            for (int j = 0; j < 4; j++) {
                short8 bk = *(const short8*)(Kcur + (j * 16 + l16) * 128 + d * 32 + quad * 8);
                S[j] = __builtin_amdgcn_mfma_f32_16x16x32_bf16(qf[d], bk, S[j], 0, 0, 0);
            }
        }
        // P = exp(s*scale); causal mask -> 0
        const int qbase = wq0 + quad * 4;
        const int kvb = kt * 64 + l16;
        const bool diag = (kt * 64 + 63 > wq0);
#pragma unroll
        for (int j = 0; j < 4; j++)
#pragma unroll
            for (int r = 0; r < 4; r++) {
                bool masked = diag && (kvb + j * 16 > qbase + r);
                float p = masked ? 0.f : __expf(S[j][r] * scale);
                Ps[wave][(quad * 4 + r) * PS_STRIDE + j * 16 + l16] = f2b(p);
            }
        // per-wave LDS RAW fence before cross-lane reads of Ps[wave]
        __asm__ volatile("s_waitcnt lgkmcnt(0)" ::: "memory");
        // O += P(16x64) @ V(64x128); l += P @ ones
#pragma unroll
        for (int ks = 0; ks < 2; ks++) {
            short8 ap = *(const short8*)(Ps[wave] + l16 * PS_STRIDE + ks * 32 + quad * 8);
#pragma unroll
            for (int dt = 0; dt < 8; dt++) {
                short8 bv = *(const short8*)(Vs + (dt * 16 + l16) * VS_STRIDE + ks * 32 + quad * 8);
                Oacc[dt] = __builtin_amdgcn_mfma_f32_16x16x32_bf16(ap, bv, Oacc[dt], 0, 0, 0);
            }
            Oacc[8] = __builtin_amdgcn_mfma_f32_16x16x32_bf16(ap, ONES, Oacc[8], 0, 0, 0);
        }
    }
    // epilogue: y bf16 [b*T + q][h*128 + d]; normalize by l = Oacc[8]
#pragma unroll
    for (int dt = 0; dt < 8; dt++)
#pragma unroll
        for (int r = 0; r < 4; r++) {
            float v = Oacc[dt][r] / Oacc[8][r];
            y[(size_t)(b * TT + wq0 + quad * 4 + r) * D_MODEL
              + h * 128 + dt * 16 + l16] = f2b(v);
        }
}

// ---------------------------------------------------------------------------
// Memory plan (ws use = 25,165,824 B, proven available; inputs/out fp32):
//   ws[0, 16.78M):      xb (phases 1-4) -> Y (attn -> gemm2)
//   ws[16.78M, 25.17M): WqkvT rows 0..2047 (gemm1) -> WoT (gemm2)
//   d_out[0, 25.17M):   QKV bf16 (gemm1 -> attn) -> final fp32 out (gemm2)
//   d_out[25.17M, 33.55M): WqkvT rows 2048..3071 (gemm1 only; dead after)
extern "C" void kernel_launch(void* const* d_in, const int* in_sizes, int n_in,
                              void* d_out, int out_size, void* d_ws, size_t ws_size,
                              hipStream_t stream) {
    const float* x    = (const float*)d_in[0];   // 4096 x 2048 fp32
    const float* Wqkv = (const float*)d_in[1];   // 2048 x 3072 fp32
    const float* Wo   = (const float*)d_in[2];   // 2048 x 2048 fp32
    const int*   sp   = (const int*)d_in[3];

    char* ws = (char*)d_ws;
    char* dob = (char*)d_out;
    u16*   xb     = (u16*)ws;                    // 4096x2048 bf16
    u16*   Y      = (u16*)ws;                    //    (after gemm1: attn output)
    u16*   WqkvTA = (u16*)(ws + 16777216);       // N-rows 0..2047 of Wqkv^T
    u16*   WoT    = (u16*)(ws + 16777216);       //    (after gemm1)
    u16*   QKV    = (u16*)d_out;                 // 4096x3072 bf16
    u16*   WqkvTB = (u16*)(dob + 25165824);      // N-rows 2048..3071 of Wqkv^T
    float* out    = (float*)d_out;

    // 1. x -> bf16
    convert_f2b<<<ROWS * D_MODEL / 4 / 256, 256, 0, stream>>>(x, xb);
    // 2. Wqkv^T split across the two scratch tails
    transpose_f2b<<<dim3(64, 64), 256, 0, stream>>>(Wqkv, WqkvTA, D_MODEL, QKV_DIM, 0);
    transpose_f2b<<<dim3(32, 64), 256, 0, stream>>>(Wqkv, WqkvTB, D_MODEL, QKV_DIM, 2048);
    // 3. QKV = x @ Wqkv with fused RoPE (async m97 structure, fast trig)
    gemm_bt_async<false, true><<<dim3(QKV_DIM / 128, ROWS / 128), 256, 0, stream>>>(
        xb, WqkvTA, WqkvTB, 2048, QKV, ROWS, QKV_DIM, D_MODEL, sp);
    // 4. Wo^T (overwrites WqkvTA, dead)
    transpose_f2b<<<dim3(64, 64), 256, 0, stream>>>(Wo, WoT, D_MODEL, D_MODEL, 0);
    // 5. flash attention -> Y (overwrites xb, dead)
    attn_kernel<<<512, 512, 0, stream>>>(QKV, Y);
    // 6. out = Y @ Wo -> fp32 (overwrites QKV + WqkvTB, dead)
    gemm_bt_async<true, false><<<dim3(D_MODEL / 128, ROWS / 128), 256, 0, stream>>>(
        Y, WoT, WoT, D_MODEL, out, ROWS, D_MODEL, D_MODEL, sp);
}

// Round 9
// 359.060 us; speedup vs baseline: 1.1600x; 1.1600x over previous
//
#include <hip/hip_runtime.h>
#include <math.h>

// Problem constants
#define D_MODEL 2048
#define N_HEADS 16
#define N_KV    4
#define DH      128
#define QKV_DIM 3072   // 2048 + 2*4*128
#define TT      2048   // T
#define BB      2      // B
#define ROWS    (BB*TT)  // 4096

// LDS strides (u16 units)
#define VS_STRIDE 72    // 128 rows (d) x 64 kv (padded)
#define PS_STRIDE 72    // 16 rows (q) x 64 kv (padded)

typedef unsigned short u16;
typedef short short8 __attribute__((ext_vector_type(8)));
typedef short short4v __attribute__((ext_vector_type(4)));
typedef float float4v __attribute__((ext_vector_type(4)));

__device__ inline float b2f(u16 h) {
    union { unsigned u; float f; } v; v.u = ((unsigned)h) << 16; return v.f;
}
__device__ inline u16 f2b(float f) {
    union { float f; unsigned u; } v; v.f = f;
    unsigned r = v.u + 0x7FFF + ((v.u >> 16) & 1);
    return (u16)(r >> 16);
}

// async global->LDS DMA, 16 bytes/lane. LDS dest = wave-uniform base + lane*16.
__device__ inline void async16(const void* g, void* l) {
    __builtin_amdgcn_global_load_lds(
        (const __attribute__((address_space(1))) void*)g,
        (__attribute__((address_space(3))) void*)l, 16, 0, 0);
}

// ---------------------------------------------------------------------------
// fp32 -> bf16 bulk convert (vectorized)
__global__ void convert_f2b(const float* __restrict__ src, u16* __restrict__ dst) {
    int i = blockIdx.x * 256 + threadIdx.x;
    float4v a = *(const float4v*)(src + (size_t)i * 4);
    short4v p;
    p[0] = (short)f2b(a[0]); p[1] = (short)f2b(a[1]);
    p[2] = (short)f2b(a[2]); p[3] = (short)f2b(a[3]);
    *(short4v*)(dst + (size_t)i * 4) = p;
}

// ---------------------------------------------------------------------------
// 32x32 transpose + fp32->bf16: dst[c][r] = bf16(src[r][c + col0]). 256 thr.
__global__ void transpose_f2b(const float* __restrict__ src, u16* __restrict__ dst,
                              int R, int C, int col0) {
    __shared__ __align__(16) u16 tile[32][33];
    int bc = blockIdx.x * 32, br = blockIdx.y * 32;
    int tx = threadIdx.x & 31, ty = threadIdx.x >> 5;   // ty 0..7
    for (int i = ty; i < 32; i += 8)
        tile[i][tx] = f2b(src[(size_t)(br + i) * C + col0 + bc + tx]);
    __syncthreads();
    for (int i = ty; i < 32; i += 8)
        dst[(size_t)(bc + i) * R + br + tx] = tile[tx][i];
}

// ---------------------------------------------------------------------------
// m97-style async GEMM: C[M,N] = A[M,K] @ Bt[N,K]^T, bf16 in, fp32 accum.
// B^T split across two buffers at N-row `nsplit` (workspace tetris).
// ROPE: fused rotary on cols < 2560 (fast hw trig: __sinf/__cosf/__expf).
template<bool F32OUT, bool ROPE>
__global__ __launch_bounds__(256) void gemm_bt_async(
    const u16* __restrict__ A, const u16* __restrict__ Bt1, const u16* __restrict__ Bt2,
    int nsplit, void* __restrict__ Cv, int M, int N, int K, const int* __restrict__ sp) {
    __shared__ __align__(16) u16 As[128 * 32];
    __shared__ __align__(16) u16 Bs[128 * 32];
    const int tid = threadIdx.x;
    const int wave = tid >> 6, lane = tid & 63;
    const int quad = lane >> 4, l16 = lane & 15;
    const int bm = blockIdx.y * 128, bn = blockIdx.x * 128;
    const int wm = (wave >> 1) * 64, wn = (wave & 1) * 64;
    const int srow = wave * 32 + (lane >> 2);
    const int scol = (lane & 3) * 8;
    const u16* Bt = (bn < nsplit) ? (Bt1 + (size_t)bn * K)
                                  : (Bt2 + (size_t)(bn - nsplit) * K);

    float4v acc[4][4] = {};

    for (int k0 = 0; k0 < K; k0 += 32) {
        async16(A + (size_t)(bm + srow) * K + k0 + scol, (char*)As + wave * 2048);
        async16(A + (size_t)(bm + srow + 16) * K + k0 + scol, (char*)As + wave * 2048 + 1024);
        async16(Bt + (size_t)srow * K + k0 + scol, (char*)Bs + wave * 2048);
        async16(Bt + (size_t)(srow + 16) * K + k0 + scol, (char*)Bs + wave * 2048 + 1024);
        __syncthreads();
        short8 af[4], bf[4];
#pragma unroll
        for (int i = 0; i < 4; i++)
            af[i] = *(const short8*)(As + (wm + i * 16 + l16) * 32 + quad * 8);
#pragma unroll
        for (int j = 0; j < 4; j++)
            bf[j] = *(const short8*)(Bs + (wn + j * 16 + l16) * 32 + quad * 8);
#pragma unroll
        for (int i = 0; i < 4; i++)
#pragma unroll
            for (int j = 0; j < 4; j++)
                acc[i][j] = __builtin_amdgcn_mfma_f32_16x16x32_bf16(af[i], bf[j], acc[i][j], 0, 0, 0);
        __syncthreads();
    }
    const int sp0 = ROPE ? *sp : 0;
    // epilogue: C/D layout col=lane&15, row=quad*4+reg (m89/m91-verified).
#pragma unroll
    for (int j = 0; j < 4; j++) {
        int col = bn + wn + j * 16 + l16;
        bool do_rope = ROPE && (col < 2560);
        float inv = 0.f;
        if (do_rope) inv = __expf(-0.14391156816f * (float)((col & 127) >> 1));
#pragma unroll
        for (int i = 0; i < 4; i++) {
            int row0 = bm + wm + i * 16 + quad * 4;
#pragma unroll
            for (int r = 0; r < 4; r++) {
                float v = acc[i][j][r];
                if (do_rope) {
                    float partner = __shfl_xor(v, 1, 64);
                    float ang = (float)(sp0 + ((row0 + r) & (TT - 1))) * inv;
                    float c = __cosf(ang), s = __sinf(ang);
                    v = (col & 1) ? (partner * s + v * c)
                                  : (v * c - partner * s);
                }
                if (F32OUT) ((float*)Cv)[(size_t)(row0 + r) * N + col] = v;
                else        ((u16*)Cv)[(size_t)(row0 + r) * N + col] = f2b(v);
            }
        }
    }
}

// ---------------------------------------------------------------------------
// Flash attention v6: 512 threads = 8 waves, q-tile 128 rows (16/wave).
// K staged via global_load_lds double-buffer with XOR-SWIZZLED layout:
//   LDS[row][c] = global[row][c ^ (row&7)]  (c = 8-u16 chunk index)
// -> fragment reads hit 8 lanes per 4-bank group (m97-equivalent, conflict-
// free for b128). Swizzle costs nothing: it just permutes each lane's DMA
// source. XCD swizzle bx&7 -> (b,hk). Fixed-offset softmax; l via ones MFMA.
__global__ __launch_bounds__(512) void attn_kernel(
    const u16* __restrict__ qkv, u16* __restrict__ y) {
    __shared__ __align__(16) u16 Ks[2][64 * 128];          // 2 x 16384 B
    __shared__ __align__(16) u16 Vs[128 * VS_STRIDE];      // 18432 B
    __shared__ __align__(16) u16 Ps[8][16 * PS_STRIDE];    // 18432 B (total 69632)

    const int tid = threadIdx.x;
    const int wave = tid >> 6, lane = tid & 63;
    const int quad = lane >> 4, l16 = lane & 15;
    const int bx = blockIdx.x;
    const int xg = bx & 7;             // XCD group = (b, hk)
    const int b = xg >> 2, hk = xg & 3;
    const int jj = bx >> 3;            // 0..63 within group
    const int h = hk * 4 + (jj & 3);
    const int qq = jj >> 2;            // 0..15
    const int qt = (qq & 1) ? (15 - (qq >> 1)) : (qq >> 1);   // balance long/short
    const int qcol = h * 128;
    const int kcol = 2048 + hk * 128;
    const int vcol = 2560 + hk * 128;
    const float scale = 0.08838834764831845f;  // 1/sqrt(128)

    // Q fragments in registers (reused every kv-tile)
    const int wq0 = qt * 128 + wave * 16;
    const u16* qrow = qkv + (size_t)(b * TT + wq0 + l16) * QKV_DIM + qcol;
    short8 qf[4];
#pragma unroll
    for (int d = 0; d < 4; d++)
        qf[d] = *(const short8*)(qrow + d * 32 + quad * 8);

    // Oacc[0..7]: O tile (16 x 128). Oacc[8]: row-sum l via ones-column.
    float4v Oacc[9] = {};
    const short8 ONES = {(short)0x3F80, (short)0x3F80, (short)0x3F80, (short)0x3F80,
                         (short)0x3F80, (short)0x3F80, (short)0x3F80, (short)0x3F80};

    const int ktmax = 2 * qt + 1;

    // K DMA source offsets with XOR swizzle. Instruction s covers LDS rows
    // wave*8 + s*4 + (lane>>4), chunk lane&15; source chunk = (lane&15)^(row&7).
    size_t kg[2];
#pragma unroll
    for (int s = 0; s < 2; s++) {
        int rl = s * 4 + (lane >> 4);          // row&7 (wave*8 is 0 mod 8)
        kg[s] = (size_t)(wave * 8 + rl) * QKV_DIM + (size_t)(((lane & 15) ^ rl) * 8);
    }
    // kt=0 prefetch: K via DMA, V via registers
    {
        const u16* kb = qkv + (size_t)(b * TT) * QKV_DIM + kcol;
        async16(kb + kg[0], (char*)Ks[0] + wave * 2048);
        async16(kb + kg[1], (char*)Ks[0] + wave * 2048 + 1024);
    }
    short8 vreg[2];
#pragma unroll
    for (int s = 0; s < 2; s++)
        vreg[s] = *(const short8*)(qkv + (size_t)(b * TT + lane) * QKV_DIM + vcol + (wave * 2 + s) * 8);

    for (int kt = 0; kt <= ktmax; kt++) {
        const u16* Kcur = Ks[kt & 1];
        __syncthreads();   // drains K-DMA + V prefetch; prev tile's readers done
        // commit V (transposed) to LDS: consecutive-u16 stores, conflict-free
#pragma unroll
        for (int s = 0; s < 2; s++) {
            int dgi = wave * 2 + s;
#pragma unroll
            for (int j8 = 0; j8 < 8; j8++)
                Vs[(dgi * 8 + j8) * VS_STRIDE + lane] = (u16)vreg[s][j8];
        }
        __syncthreads();   // Vs visible
        if (kt < ktmax) {  // prefetch next tile (overlaps all compute below)
            const u16* kb = qkv + (size_t)(b * TT + (kt + 1) * 64) * QKV_DIM;
            async16(kb + kcol + kg[0], (char*)Ks[(kt + 1) & 1] + wave * 2048);
            async16(kb + kcol + kg[1], (char*)Ks[(kt + 1) & 1] + wave * 2048 + 1024);
#pragma unroll
            for (int s = 0; s < 2; s++)
                vreg[s] = *(const short8*)(kb + (size_t)lane * QKV_DIM + vcol + (wave * 2 + s) * 8);
        }

        // S = Q*K^T  (K read through the XOR swizzle: chunk = (d*4+quad)^(l16&7))
        float4v S[4] = {};
#pragma unroll
        for (int d = 0; d < 4; d++) {
#pragma unroll
            for (int j = 0; j < 4; j++) {
                short8 bk = *(const short8*)(Kcur + (j * 16 + l16) * 128
                                             + (((d * 4 + quad) ^ (l16 & 7)) * 8));
                S[j] = __builtin_amdgcn_mfma_f32_16x16x32_bf16(qf[d], bk, S[j], 0, 0, 0);
            }
        }
        // P = exp(s*scale); causal mask -> 0
        const int qbase = wq0 + quad * 4;
        const int kvb = kt * 64 + l16;
        const bool diag = (kt * 64 + 63 > wq0);
#pragma unroll
        for (int j = 0; j < 4; j++)
#pragma unroll
            for (int r = 0; r < 4; r++) {
                bool masked = diag && (kvb + j * 16 > qbase + r);
                float p = masked ? 0.f : __expf(S[j][r] * scale);
                Ps[wave][(quad * 4 + r) * PS_STRIDE + j * 16 + l16] = f2b(p);
            }
        // per-wave LDS RAW fence before cross-lane reads of Ps[wave]
        __asm__ volatile("s_waitcnt lgkmcnt(0)" ::: "memory");
        // O += P(16x64) @ V(64x128); l += P @ ones
#pragma unroll
        for (int ks = 0; ks < 2; ks++) {
            short8 ap = *(const short8*)(Ps[wave] + l16 * PS_STRIDE + ks * 32 + quad * 8);
#pragma unroll
            for (int dt = 0; dt < 8; dt++) {
                short8 bv = *(const short8*)(Vs + (dt * 16 + l16) * VS_STRIDE + ks * 32 + quad * 8);
                Oacc[dt] = __builtin_amdgcn_mfma_f32_16x16x32_bf16(ap, bv, Oacc[dt], 0, 0, 0);
            }
            Oacc[8] = __builtin_amdgcn_mfma_f32_16x16x32_bf16(ap, ONES, Oacc[8], 0, 0, 0);
        }
    }
    // epilogue: y bf16 [b*T + q][h*128 + d]; normalize by l = Oacc[8]
#pragma unroll
    for (int dt = 0; dt < 8; dt++)
#pragma unroll
        for (int r = 0; r < 4; r++) {
            float v = Oacc[dt][r] / Oacc[8][r];
            y[(size_t)(b * TT + wq0 + quad * 4 + r) * D_MODEL
              + h * 128 + dt * 16 + l16] = f2b(v);
        }
}

// ---------------------------------------------------------------------------
// Memory plan (ws use = 25,165,824 B, proven available; inputs/out fp32):
//   ws[0, 16.78M):      xb (phases 1-4) -> Y (attn -> gemm2)
//   ws[16.78M, 25.17M): WqkvT rows 0..2047 (gemm1) -> WoT (gemm2)
//   d_out[0, 25.17M):   QKV bf16 (gemm1 -> attn) -> final fp32 out (gemm2)
//   d_out[25.17M, 33.55M): WqkvT rows 2048..3071 (gemm1 only; dead after)
extern "C" void kernel_launch(void* const* d_in, const int* in_sizes, int n_in,
                              void* d_out, int out_size, void* d_ws, size_t ws_size,
                              hipStream_t stream) {
    const float* x    = (const float*)d_in[0];   // 4096 x 2048 fp32
    const float* Wqkv = (const float*)d_in[1];   // 2048 x 3072 fp32
    const float* Wo   = (const float*)d_in[2];   // 2048 x 2048 fp32
    const int*   sp   = (const int*)d_in[3];

    char* ws = (char*)d_ws;
    char* dob = (char*)d_out;
    u16*   xb     = (u16*)ws;                    // 4096x2048 bf16
    u16*   Y      = (u16*)ws;                    //    (after gemm1: attn output)
    u16*   WqkvTA = (u16*)(ws + 16777216);       // N-rows 0..2047 of Wqkv^T
    u16*   WoT    = (u16*)(ws + 16777216);       //    (after gemm1)
    u16*   QKV    = (u16*)d_out;                 // 4096x3072 bf16
    u16*   WqkvTB = (u16*)(dob + 25165824);      // N-rows 2048..3071 of Wqkv^T
    float* out    = (float*)d_out;

    // 1. x -> bf16
    convert_f2b<<<ROWS * D_MODEL / 4 / 256, 256, 0, stream>>>(x, xb);
    // 2. Wqkv^T split across the two scratch tails
    transpose_f2b<<<dim3(64, 64), 256, 0, stream>>>(Wqkv, WqkvTA, D_MODEL, QKV_DIM, 0);
    transpose_f2b<<<dim3(32, 64), 256, 0, stream>>>(Wqkv, WqkvTB, D_MODEL, QKV_DIM, 2048);
    // 3. QKV = x @ Wqkv with fused RoPE (async m97 structure, fast trig)
    gemm_bt_async<false, true><<<dim3(QKV_DIM / 128, ROWS / 128), 256, 0, stream>>>(
        xb, WqkvTA, WqkvTB, 2048, QKV, ROWS, QKV_DIM, D_MODEL, sp);
    // 4. Wo^T (overwrites WqkvTA, dead)
    transpose_f2b<<<dim3(64, 64), 256, 0, stream>>>(Wo, WoT, D_MODEL, D_MODEL, 0);
    // 5. flash attention -> Y (overwrites xb, dead)
    attn_kernel<<<512, 512, 0, stream>>>(QKV, Y);
    // 6. out = Y @ Wo -> fp32 (overwrites QKV + WqkvTB, dead)
    gemm_bt_async<true, false><<<dim3(D_MODEL / 128, ROWS / 128), 256, 0, stream>>>(
        Y, WoT, WoT, D_MODEL, out, ROWS, D_MODEL, D_MODEL, sp);
}